// Round 1
// baseline (137.006 us; speedup 1.0000x reference)
//
#include <hip/hip_runtime.h>

#define T_TILES 64
#define NB      128
#define M_TOTAL 8192
#define RESULT_FLOATS (M_TOTAL * 7)

// ---------------------------------------------------------------------------
// Kernel 1: per-tile class-aware greedy NMS (exact replication of reference
// arithmetic). One block per tile, one thread per box.
// Outputs per global box index: sbits (sort key) and keep flag.
// ---------------------------------------------------------------------------
__global__ __launch_bounds__(NB) void tile_nms_kernel(
    const float* __restrict__ tile_results,   // [64][128][7]
    const int*   __restrict__ tile_positions, // [64][4] (h0,h1,w0,w1)
    unsigned int* __restrict__ sbits_g,       // [8192]
    unsigned int* __restrict__ keep_g)        // [8192]
{
    const int t = blockIdx.x;
    const int n = threadIdx.x;

    __shared__ unsigned int s_sb[NB];
    __shared__ float t_x1[NB], t_y1[NB], t_x2[NB], t_y2[NB], t_area[NB];
    __shared__ unsigned long long validmask[2];
    __shared__ unsigned long long sup[NB][2];
    __shared__ unsigned long long keepmask[2];

    const float* row = tile_results + (size_t)(t * NB + n) * 7;
    float x1 = row[0], y1 = row[1], x2 = row[2], y2 = row[3];
    float score = row[4], label = row[5];

    float hf = (float)tile_positions[t * 4 + 0];   // h_start
    float wf = (float)tile_positions[t * 4 + 2];   // w_start

    // boxes = clip(boxes + [w,h,w,h], 0, 4096)  -- IEEE rn, no contraction
    float gx1 = fminf(fmaxf(__fadd_rn(x1, wf), 0.0f), 4096.0f);
    float gy1 = fminf(fmaxf(__fadd_rn(y1, hf), 0.0f), 4096.0f);
    float gx2 = fminf(fmaxf(__fadd_rn(x2, wf), 0.0f), 4096.0f);
    float gy2 = fminf(fmaxf(__fadd_rn(y2, hf), 0.0f), 4096.0f);

    bool valid = score > 0.05f;
    unsigned int sb = valid ? __float_as_uint(score) : 0u;

    // class shift: + label * 2*IMAGE_SIZE on all 4 coords (rounded like ref)
    float c = __fmul_rn(label, 8192.0f);
    float sx1 = __fadd_rn(gx1, c);
    float sy1 = __fadd_rn(gy1, c);
    float sx2 = __fadd_rn(gx2, c);
    float sy2 = __fadd_rn(gy2, c);
    float area = __fmul_rn(__fsub_rn(sx2, sx1), __fsub_rn(sy2, sy1));

    s_sb[n] = sb;
    if (n < 2) validmask[n] = 0ull;
    __syncthreads();

    // local stable rank: (sbits desc, index asc)
    int p = 0;
#pragma unroll 8
    for (int u = 0; u < NB; ++u) {
        unsigned int su = s_sb[u];
        p += (su > sb) || (su == sb && u < n);
    }

    // scatter into sorted-slot arrays
    t_x1[p] = sx1; t_y1[p] = sy1; t_x2[p] = sx2; t_y2[p] = sy2; t_area[p] = area;
    if (valid) atomicOr(&validmask[p >> 6], 1ull << (p & 63));
    __syncthreads();

    // suppression row for my sorted slot p: bit w set if w > p and IoU > 0.5
    unsigned long long m0 = 0ull, m1 = 0ull;
#pragma unroll 4
    for (int w = 0; w < NB; ++w) {
        float ltx = fmaxf(sx1, t_x1[w]);
        float lty = fmaxf(sy1, t_y1[w]);
        float rbx = fminf(sx2, t_x2[w]);
        float rby = fminf(sy2, t_y2[w]);
        float iw = fmaxf(__fsub_rn(rbx, ltx), 0.0f);
        float ih = fmaxf(__fsub_rn(rby, lty), 0.0f);
        float inter = __fmul_rn(iw, ih);
        // union = (area_i + area_j) - inter ; iou = inter / (union + 1e-8)
        float uni   = __fsub_rn(__fadd_rn(area, t_area[w]), inter);
        float denom = __fadd_rn(uni, 1e-8f);
        float iou   = __fdiv_rn(inter, denom);
        bool s = (w > p) && (iou > 0.5f);
        if (s) {
            if (w < 64) m0 |= (1ull << w);
            else        m1 |= (1ull << (w - 64));
        }
    }
    sup[p][0] = m0;
    sup[p][1] = m1;
    __syncthreads();

    // single-thread greedy scan over 128 sorted slots
    if (n == 0) {
        unsigned long long v0 = validmask[0], v1 = validmask[1];
        unsigned long long r0 = 0ull, r1 = 0ull;
#pragma unroll 8
        for (int q = 0; q < NB; ++q) {
            unsigned long long s0 = sup[q][0];
            unsigned long long s1 = sup[q][1];
            bool vbit = (q < 64) ? ((v0 >> q) & 1ull) : ((v1 >> (q - 64)) & 1ull);
            bool rbit = (q < 64) ? ((r0 >> q) & 1ull) : ((r1 >> (q - 64)) & 1ull);
            unsigned long long take = (vbit && !rbit) ? ~0ull : 0ull;
            r0 |= (s0 & take);
            r1 |= (s1 & take);
        }
        keepmask[0] = v0 & ~r0;
        keepmask[1] = v1 & ~r1;
    }
    __syncthreads();

    bool keep = ((keepmask[p >> 6] >> (p & 63)) & 1ull) != 0ull;
    int gid = t * NB + n;
    sbits_g[gid] = sb;
    keep_g[gid]  = keep ? 1u : 0u;
}

// ---------------------------------------------------------------------------
// Kernel 2: global rank (stable count) + scatter output rows.
// 256 blocks x 128 threads; 4 threads per box, each scans 1/4 of the keys.
// ---------------------------------------------------------------------------
__global__ __launch_bounds__(128) void rank_write_kernel(
    const float* __restrict__ tile_results,
    const int*   __restrict__ tile_positions,
    const unsigned int* __restrict__ sbits_g,
    const unsigned int* __restrict__ keep_g,
    float* __restrict__ out)   // [8192*7] result rows, then [8192] keep flags
{
    __shared__ uint4 s_keys4[M_TOTAL / 4];   // 32 KB
    __shared__ int   s_part[128];

    const int tid = threadIdx.x;

    // stage all keys
    const uint4* g4 = (const uint4*)sbits_g;
    for (int k = tid; k < M_TOTAL / 4; k += 128) s_keys4[k] = g4[k];
    __syncthreads();

    const int local   = tid >> 2;              // 0..31
    const int quarter = tid & 3;               // 0..3
    const int i = blockIdx.x * 32 + local;     // global box id

    const unsigned int* s_keys = (const unsigned int*)s_keys4;
    unsigned int mykey = s_keys[i];

    int cnt = 0;
    int base = quarter * (M_TOTAL / 16);       // uint4 index
#pragma unroll 4
    for (int k = 0; k < M_TOTAL / 16; ++k) {
        uint4 v = s_keys4[base + k];
        int j0 = (base + k) * 4;
        cnt += (v.x > mykey) + (v.y > mykey) + (v.z > mykey) + (v.w > mykey);
        cnt += ((v.x == mykey) && (j0     < i))
             + ((v.y == mykey) && (j0 + 1 < i))
             + ((v.z == mykey) && (j0 + 2 < i))
             + ((v.w == mykey) && (j0 + 3 < i));
    }
    s_part[tid] = cnt;
    __syncthreads();

    if (quarter == 0) {
        int rank = s_part[tid] + s_part[tid + 1] + s_part[tid + 2] + s_part[tid + 3];

        const float* row = tile_results + (size_t)i * 7;
        float x1 = row[0], y1 = row[1], x2 = row[2], y2 = row[3];
        float score = row[4], label = row[5], growth = row[6];

        const int t = i >> 7;
        float hf = (float)tile_positions[t * 4 + 0];
        float wf = (float)tile_positions[t * 4 + 2];

        float gx1 = fminf(fmaxf(__fadd_rn(x1, wf), 0.0f), 4096.0f);
        float gy1 = fminf(fmaxf(__fadd_rn(y1, hf), 0.0f), 4096.0f);
        float gx2 = fminf(fmaxf(__fadd_rn(x2, wf), 0.0f), 4096.0f);
        float gy2 = fminf(fmaxf(__fadd_rn(y2, hf), 0.0f), 4096.0f);

        float kf = keep_g[i] ? 1.0f : 0.0f;

        float* o = out + (size_t)rank * 7;
        o[0] = __fmul_rn(gx1, kf);
        o[1] = __fmul_rn(gy1, kf);
        o[2] = __fmul_rn(gx2, kf);
        o[3] = __fmul_rn(gy2, kf);
        o[4] = __fmul_rn(score, kf);
        o[5] = __fmul_rn(label, kf);
        o[6] = __fmul_rn(growth, kf);
        out[RESULT_FLOATS + rank] = kf;
    }
}

extern "C" void kernel_launch(void* const* d_in, const int* in_sizes, int n_in,
                              void* d_out, int out_size, void* d_ws, size_t ws_size,
                              hipStream_t stream) {
    const float* tile_results  = (const float*)d_in[0];
    const int*   tile_positions = (const int*)d_in[1];
    float* out = (float*)d_out;

    unsigned int* sbits = (unsigned int*)d_ws;          // 32 KB
    unsigned int* keep  = sbits + M_TOTAL;              // 32 KB

    hipLaunchKernelGGL(tile_nms_kernel, dim3(T_TILES), dim3(NB), 0, stream,
                       tile_results, tile_positions, sbits, keep);
    hipLaunchKernelGGL(rank_write_kernel, dim3(M_TOTAL / 32), dim3(128), 0, stream,
                       tile_results, tile_positions, sbits, keep, out);
}

// Round 3
// 75.477 us; speedup vs baseline: 1.8152x; 1.8152x over previous
//
#include <hip/hip_runtime.h>

#define NB       128
#define M_TOTAL  8192
#define HALF_M   4096
#define RESULT_FLOATS (M_TOTAL * 7)

typedef unsigned long long u64;
typedef unsigned int u32;

// One fused kernel. Grid = 256 blocks x 512 threads.
//   block b: tile tb = b>>2 (4 blocks per tile), sub = b&3.
//   - All 4 sibling blocks redundantly run the tile's NMS (cheap).
//   - Each block computes global ranks + writes output for its 32 boxes
//     (sub*32 .. sub*32+31), 16 threads per box.
// Global order key (tie-free, stable): aug = (sbits << 13) | (8191 - j),
// where sbits = valid ? bits(score) : 0. rank_i = #{j : aug_j > aug_i}.
__global__ __launch_bounds__(512) void fused_nms_kernel(
    const float* __restrict__ tr,    // [8192][7]
    const int*   __restrict__ tp,    // [64][4]
    float*       __restrict__ out)   // [8192*7] rows + [8192] keep
{
    __shared__ alignas(16) u64 s_aug[HALF_M];          // 32 KB (2 passes)
    __shared__ u64   s_laug[NB];                       // tile-local keys
    __shared__ float t_x1[NB], t_y1[NB], t_x2[NB], t_y2[NB], t_area[NB];
    __shared__ alignas(16) u32 sup32[NB][4];           // suppression bitmatrix
    __shared__ u64   validmask[2];
    __shared__ u64   keepmask[2];
    __shared__ int   s_cnt[512];
    __shared__ int   s_p[NB];

    const int tid = threadIdx.x;
    const int sub = blockIdx.x & 3;
    const int tb  = blockIdx.x >> 2;
    const int g0  = tb * NB;

    if (tid < 2) validmask[tid] = 0ull;

    // ---- my rank-scan box: i = g0 + sub*32 + (tid>>4), 16 threads each ----
    const int n16  = tid >> 4;          // 0..31
    const int part = tid & 15;          // 0..15
    const int ibox = g0 + sub * 32 + n16;
    u64 myaug;
    {
        float sc = tr[(size_t)ibox * 7 + 4];
        u32 sb = (sc > 0.05f) ? __float_as_uint(sc) : 0u;
        myaug = ((u64)sb << 13) | (u64)(M_TOTAL - 1 - ibox);
    }

    // ---- per-box full compute for this tile's NMS (threads 0..127) ----
    float sx1 = 0.f, sy1 = 0.f, sx2 = 0.f, sy2 = 0.f, area = 0.f;
    u64 aug_n = 0;
    bool valid = false;
    if (tid < NB) {
        const float* row = tr + (size_t)(g0 + tid) * 7;
        float x1 = row[0], y1 = row[1], x2 = row[2], y2 = row[3];
        float score = row[4], label = row[5];
        float hf = (float)tp[tb * 4 + 0];
        float wf = (float)tp[tb * 4 + 2];
        float gx1 = fminf(fmaxf(__fadd_rn(x1, wf), 0.0f), 4096.0f);
        float gy1 = fminf(fmaxf(__fadd_rn(y1, hf), 0.0f), 4096.0f);
        float gx2 = fminf(fmaxf(__fadd_rn(x2, wf), 0.0f), 4096.0f);
        float gy2 = fminf(fmaxf(__fadd_rn(y2, hf), 0.0f), 4096.0f);
        valid = score > 0.05f;
        u32 sb = valid ? __float_as_uint(score) : 0u;
        aug_n = ((u64)sb << 13) | (u64)(M_TOTAL - 1 - (g0 + tid));
        float c = __fmul_rn(label, 8192.0f);
        sx1 = __fadd_rn(gx1, c);
        sy1 = __fadd_rn(gy1, c);
        sx2 = __fadd_rn(gx2, c);
        sy2 = __fadd_rn(gy2, c);
        area = __fmul_rn(__fsub_rn(sx2, sx1), __fsub_rn(sy2, sy1));
        s_laug[tid] = aug_n;
    }

    // ---- stage pass-1 keys: global boxes [0, 4096) ----
#pragma unroll
    for (int x = 0; x < 8; ++x) {
        int j = tid + 512 * x;
        float sc = tr[(size_t)j * 7 + 4];
        u32 sb = (sc > 0.05f) ? __float_as_uint(sc) : 0u;
        s_aug[j] = ((u64)sb << 13) | (u64)(M_TOTAL - 1 - j);
    }
    __syncthreads();

    // ---- rank scan pass 1 (all 512 threads) ----
    int cnt = 0;
    {
        const ulonglong2* av = (const ulonglong2*)s_aug;
#pragma unroll 4
        for (int k = 0; k < 128; ++k) {
            ulonglong2 v = av[part + 16 * k];
            cnt += (v.x > myaug) + (v.y > myaug);
        }
    }

    // ---- local stable rank (threads 0..127) ----
    int p = 0;
    if (tid < NB) {
#pragma unroll 8
        for (int u = 0; u < NB; ++u) p += (s_laug[u] > aug_n);
    }
    __syncthreads();   // pass-1 reads + s_laug reads complete

    // ---- scatter sorted-slot arrays; restage pass-2 keys ----
    if (tid < NB) {
        t_x1[p] = sx1; t_y1[p] = sy1; t_x2[p] = sx2; t_y2[p] = sy2;
        t_area[p] = area;
        s_p[tid] = p;
        if (valid) atomicOr(&validmask[p >> 6], 1ull << (p & 63));
    }
#pragma unroll
    for (int x = 0; x < 8; ++x) {
        int L = tid + 512 * x;
        int j = HALF_M + L;
        float sc = tr[(size_t)j * 7 + 4];
        u32 sb = (sc > 0.05f) ? __float_as_uint(sc) : 0u;
        s_aug[L] = ((u64)sb << 13) | (u64)(M_TOTAL - 1 - j);
    }
    __syncthreads();

    // ---- rank scan pass 2 ----
    {
        const ulonglong2* av = (const ulonglong2*)s_aug;
#pragma unroll 4
        for (int k = 0; k < 128; ++k) {
            ulonglong2 v = av[part + 16 * k];
            cnt += (v.x > myaug) + (v.y > myaug);
        }
    }
    s_cnt[tid] = cnt;

    // ---- suppression bitmatrix: thread -> (row r, col quarter cq) ----
    {
        int r = tid >> 2, cq = tid & 3;
        float rx1 = t_x1[r], ry1 = t_y1[r], rx2 = t_x2[r], ry2 = t_y2[r];
        float ra = t_area[r];
        u32 m = 0;
        int wbase = cq * 32;
#pragma unroll 4
        for (int w2 = 0; w2 < 32; ++w2) {
            int w = wbase + w2;
            float ltx = fmaxf(rx1, t_x1[w]);
            float lty = fmaxf(ry1, t_y1[w]);
            float rbx = fminf(rx2, t_x2[w]);
            float rby = fminf(ry2, t_y2[w]);
            float iw = fmaxf(__fsub_rn(rbx, ltx), 0.0f);
            float ih = fmaxf(__fsub_rn(rby, lty), 0.0f);
            float inter = __fmul_rn(iw, ih);
            float uni   = __fsub_rn(__fadd_rn(ra, t_area[w]), inter);
            float denom = __fadd_rn(uni, 1e-8f);
            float iou   = __fdiv_rn(inter, denom);
            bool s = (w > r) && (iou > 0.5f);
            m |= ((u32)s) << w2;
        }
        sup32[r][cq] = m;
    }
    __syncthreads();

    // ---- serial greedy scan (thread 0), 8-deep register prefetch ----
    if (tid == 0) {
        const ulonglong2* supv = (const ulonglong2*)sup32;
        u64 v0 = validmask[0], v1 = validmask[1];
        u64 r0 = 0ull, r1 = 0ull;
        for (int c = 0; c < NB; c += 8) {
            ulonglong2 buf[8];
#pragma unroll
            for (int x = 0; x < 8; ++x) buf[x] = supv[c + x];
#pragma unroll
            for (int x = 0; x < 8; ++x) {
                int q = c + x;
                u64 alive = ((q < 64) ? ((v0 & ~r0) >> q)
                                      : ((v1 & ~r1) >> (q - 64))) & 1ull;
                u64 take = 0ull - alive;
                r0 |= buf[x].x & take;
                r1 |= buf[x].y & take;
            }
        }
        keepmask[0] = v0 & ~r0;
        keepmask[1] = v1 & ~r1;
    }
    __syncthreads();

    // ---- write this block's 32 boxes ----
    if (tid < 32) {
        int nl = sub * 32 + tid;         // local box in tile
        int i  = g0 + nl;                // global box
        int rank = 0;
#pragma unroll
        for (int x = 0; x < 16; ++x) rank += s_cnt[tid * 16 + x];

        int pp = s_p[nl];
        float kf = ((keepmask[pp >> 6] >> (pp & 63)) & 1ull) ? 1.0f : 0.0f;

        const float* row = tr + (size_t)i * 7;
        float x1 = row[0], y1 = row[1], x2 = row[2], y2 = row[3];
        float score = row[4], label = row[5], growth = row[6];
        float hf = (float)tp[tb * 4 + 0];
        float wf = (float)tp[tb * 4 + 2];
        float gx1 = fminf(fmaxf(__fadd_rn(x1, wf), 0.0f), 4096.0f);
        float gy1 = fminf(fmaxf(__fadd_rn(y1, hf), 0.0f), 4096.0f);
        float gx2 = fminf(fmaxf(__fadd_rn(x2, wf), 0.0f), 4096.0f);
        float gy2 = fminf(fmaxf(__fadd_rn(y2, hf), 0.0f), 4096.0f);

        float* o = out + (size_t)rank * 7;
        o[0] = __fmul_rn(gx1, kf);
        o[1] = __fmul_rn(gy1, kf);
        o[2] = __fmul_rn(gx2, kf);
        o[3] = __fmul_rn(gy2, kf);
        o[4] = __fmul_rn(score, kf);
        o[5] = __fmul_rn(label, kf);
        o[6] = __fmul_rn(growth, kf);
        out[RESULT_FLOATS + rank] = kf;
    }
}

extern "C" void kernel_launch(void* const* d_in, const int* in_sizes, int n_in,
                              void* d_out, int out_size, void* d_ws, size_t ws_size,
                              hipStream_t stream) {
    const float* tile_results   = (const float*)d_in[0];
    const int*   tile_positions = (const int*)d_in[1];
    float* out = (float*)d_out;

    hipLaunchKernelGGL(fused_nms_kernel, dim3(256), dim3(512), 0, stream,
                       tile_results, tile_positions, out);
}

// Round 4
// 71.976 us; speedup vs baseline: 1.9035x; 1.0486x over previous
//
#include <hip/hip_runtime.h>

#define NB       128
#define M_TOTAL  8192
#define RESULT_FLOATS (M_TOTAL * 7)

typedef unsigned long long u64;
typedef unsigned int u32;

// One fused kernel. Grid = 256 blocks x 512 threads.
//   block b: tile tb = b>>2 (4 blocks per tile), sub = b&3.
//   - All 4 sibling blocks redundantly run the tile's NMS (cheap).
//   - Each block computes global ranks + writes output for its 32 boxes.
// Global order key (tie-free, stable): aug = (sbits << 13) | (8191 - j),
// sbits = valid ? bits(score) : 0. rank_i = #{j : aug_j > aug_i}.
// Rank scan is register-blocked: each thread streams 16 keys from global
// registers against the block's 32 box-keys held in VGPRs (no LDS stream).
__global__ __launch_bounds__(512) void fused_nms_kernel(
    const float* __restrict__ tr,    // [8192][7]
    const int*   __restrict__ tp,    // [64][4]
    float*       __restrict__ out)   // [8192*7] rows + [8192] keep
{
    __shared__ u64   s_boxaug[32];
    __shared__ u64   s_laug[NB];
    __shared__ float t_x1[NB], t_y1[NB], t_x2[NB], t_y2[NB], t_area[NB];
    __shared__ alignas(16) u32 sup32[NB][4];
    __shared__ u64   validmask[2];
    __shared__ u64   keepmask[2];
    __shared__ alignas(16) u32 s_wpart[8][16];   // packed u16 pairs per wave
    __shared__ int   s_p[NB];

    const int tid = threadIdx.x;
    const int sub = blockIdx.x & 3;
    const int tb  = blockIdx.x >> 2;
    const int g0  = tb * NB;

    if (tid < 2) validmask[tid] = 0ull;

    // ---- prefetch my 16 scan scores (keys j = tid + 512k) ----
    float sc[16];
#pragma unroll
    for (int k = 0; k < 16; ++k)
        sc[k] = tr[(size_t)(tid + 512 * k) * 7 + 4];

    // ---- box keys for this block's 32 output boxes ----
    if (tid < 32) {
        int i = g0 + sub * 32 + tid;
        float s = tr[(size_t)i * 7 + 4];
        u32 sb = (s > 0.05f) ? __float_as_uint(s) : 0u;
        s_boxaug[tid] = ((u64)sb << 13) | (u64)(M_TOTAL - 1 - i);
    }

    // ---- per-box NMS compute (threads 0..127) ----
    float sx1 = 0.f, sy1 = 0.f, sx2 = 0.f, sy2 = 0.f, area = 0.f;
    u64 aug_n = 0;
    bool valid = false;
    if (tid < NB) {
        const float* row = tr + (size_t)(g0 + tid) * 7;
        float x1 = row[0], y1 = row[1], x2 = row[2], y2 = row[3];
        float score = row[4], label = row[5];
        float hf = (float)tp[tb * 4 + 0];
        float wf = (float)tp[tb * 4 + 2];
        float gx1 = fminf(fmaxf(__fadd_rn(x1, wf), 0.0f), 4096.0f);
        float gy1 = fminf(fmaxf(__fadd_rn(y1, hf), 0.0f), 4096.0f);
        float gx2 = fminf(fmaxf(__fadd_rn(x2, wf), 0.0f), 4096.0f);
        float gy2 = fminf(fmaxf(__fadd_rn(y2, hf), 0.0f), 4096.0f);
        valid = score > 0.05f;
        u32 sb = valid ? __float_as_uint(score) : 0u;
        aug_n = ((u64)sb << 13) | (u64)(M_TOTAL - 1 - (g0 + tid));
        float c = __fmul_rn(label, 8192.0f);
        sx1 = __fadd_rn(gx1, c);
        sy1 = __fadd_rn(gy1, c);
        sx2 = __fadd_rn(gx2, c);
        sy2 = __fadd_rn(gy2, c);
        area = __fmul_rn(__fsub_rn(sx2, sx1), __fsub_rn(sy2, sy1));
        s_laug[tid] = aug_n;
    }
    __syncthreads();

    // ---- load the 32 box keys into registers (LDS broadcast, once) ----
    u64 bk[32];
#pragma unroll
    for (int b = 0; b < 32; ++b) bk[b] = s_boxaug[b];

    // ---- local stable rank + scatter (threads 0..127) ----
    if (tid < NB) {
        int p = 0;
        const ulonglong2* lv = (const ulonglong2*)s_laug;
#pragma unroll 8
        for (int u = 0; u < 64; ++u) {
            ulonglong2 v = lv[u];
            p += (v.x > aug_n) + (v.y > aug_n);
        }
        t_x1[p] = sx1; t_y1[p] = sy1; t_x2[p] = sx2; t_y2[p] = sy2;
        t_area[p] = area;
        s_p[tid] = p;
        if (valid) atomicOr(&validmask[p >> 6], 1ull << (p & 63));
    }

    // ---- register-blocked global rank counting ----
    int cnt[32];
#pragma unroll
    for (int b = 0; b < 32; ++b) cnt[b] = 0;
#pragma unroll
    for (int k = 0; k < 16; ++k) {
        int j = tid + 512 * k;
        u32 sb = (sc[k] > 0.05f) ? __float_as_uint(sc[k]) : 0u;
        u64 a = ((u64)sb << 13) | (u64)(M_TOTAL - 1 - j);
#pragma unroll
        for (int b = 0; b < 32; ++b) cnt[b] += (a > bk[b]);
    }

    // pack counter pairs (b, b+16) into u16 halves; totals <= 8192, no overflow
    u32 pk[16];
#pragma unroll
    for (int q = 0; q < 16; ++q)
        pk[q] = (u32)cnt[q] | ((u32)cnt[q + 16] << 16);

    // wave butterfly reduction (64 lanes)
#pragma unroll
    for (int q = 0; q < 16; ++q) {
        int c = (int)pk[q];
#pragma unroll
        for (int m = 1; m < 64; m <<= 1) c += __shfl_xor(c, m, 64);
        pk[q] = (u32)c;
    }
    {
        const int lane = tid & 63, wv = tid >> 6;
        if (lane == 0) {
            uint4* wp = (uint4*)&s_wpart[wv][0];
#pragma unroll
            for (int q4 = 0; q4 < 4; ++q4)
                wp[q4] = make_uint4(pk[4*q4], pk[4*q4+1], pk[4*q4+2], pk[4*q4+3]);
        }
    }
    __syncthreads();

    // ---- suppression bitmatrix: thread -> (row r, col quarter cq) ----
    {
        int r = tid >> 2, cq = tid & 3;
        float rx1 = t_x1[r], ry1 = t_y1[r], rx2 = t_x2[r], ry2 = t_y2[r];
        float ra = t_area[r];
        u32 m = 0;
        int wbase = cq * 32;
#pragma unroll 4
        for (int w2 = 0; w2 < 32; ++w2) {
            int w = wbase + w2;
            float ltx = fmaxf(rx1, t_x1[w]);
            float lty = fmaxf(ry1, t_y1[w]);
            float rbx = fminf(rx2, t_x2[w]);
            float rby = fminf(ry2, t_y2[w]);
            float iw = fmaxf(__fsub_rn(rbx, ltx), 0.0f);
            float ih = fmaxf(__fsub_rn(rby, lty), 0.0f);
            float inter = __fmul_rn(iw, ih);
            float uni   = __fsub_rn(__fadd_rn(ra, t_area[w]), inter);
            float denom = __fadd_rn(uni, 1e-8f);
            float iou   = __fdiv_rn(inter, denom);
            bool s = (w > r) && (iou > 0.5f);
            m |= ((u32)s) << w2;
        }
        sup32[r][cq] = m;
    }
    __syncthreads();

    // ---- serial greedy scan (thread 0), 8-deep register prefetch ----
    if (tid == 0) {
        const ulonglong2* supv = (const ulonglong2*)sup32;
        u64 v0 = validmask[0], v1 = validmask[1];
        u64 r0 = 0ull, r1 = 0ull;
        for (int c = 0; c < NB; c += 8) {
            ulonglong2 buf[8];
#pragma unroll
            for (int x = 0; x < 8; ++x) buf[x] = supv[c + x];
#pragma unroll
            for (int x = 0; x < 8; ++x) {
                int q = c + x;
                u64 alive = ((q < 64) ? ((v0 & ~r0) >> q)
                                      : ((v1 & ~r1) >> (q - 64))) & 1ull;
                u64 take = 0ull - alive;
                r0 |= buf[x].x & take;
                r1 |= buf[x].y & take;
            }
        }
        keepmask[0] = v0 & ~r0;
        keepmask[1] = v1 & ~r1;
    }
    __syncthreads();

    // ---- write this block's 32 boxes ----
    if (tid < 32) {
        int rank = 0;
        const int q = tid & 15;
        const int sh = (tid >> 4) << 4;
#pragma unroll
        for (int w = 0; w < 8; ++w)
            rank += (int)((s_wpart[w][q] >> sh) & 0xffffu);

        int nl = sub * 32 + tid;         // local box in tile
        int i  = g0 + nl;                // global box
        int pp = s_p[nl];
        float kf = ((keepmask[pp >> 6] >> (pp & 63)) & 1ull) ? 1.0f : 0.0f;

        const float* row = tr + (size_t)i * 7;
        float x1 = row[0], y1 = row[1], x2 = row[2], y2 = row[3];
        float score = row[4], label = row[5], growth = row[6];
        float hf = (float)tp[tb * 4 + 0];
        float wf = (float)tp[tb * 4 + 2];
        float gx1 = fminf(fmaxf(__fadd_rn(x1, wf), 0.0f), 4096.0f);
        float gy1 = fminf(fmaxf(__fadd_rn(y1, hf), 0.0f), 4096.0f);
        float gx2 = fminf(fmaxf(__fadd_rn(x2, wf), 0.0f), 4096.0f);
        float gy2 = fminf(fmaxf(__fadd_rn(y2, hf), 0.0f), 4096.0f);

        float* o = out + (size_t)rank * 7;
        o[0] = __fmul_rn(gx1, kf);
        o[1] = __fmul_rn(gy1, kf);
        o[2] = __fmul_rn(gx2, kf);
        o[3] = __fmul_rn(gy2, kf);
        o[4] = __fmul_rn(score, kf);
        o[5] = __fmul_rn(label, kf);
        o[6] = __fmul_rn(growth, kf);
        out[RESULT_FLOATS + rank] = kf;
    }
}

extern "C" void kernel_launch(void* const* d_in, const int* in_sizes, int n_in,
                              void* d_out, int out_size, void* d_ws, size_t ws_size,
                              hipStream_t stream) {
    const float* tile_results   = (const float*)d_in[0];
    const int*   tile_positions = (const int*)d_in[1];
    float* out = (float*)d_out;

    hipLaunchKernelGGL(fused_nms_kernel, dim3(256), dim3(512), 0, stream,
                       tile_results, tile_positions, out);
}

// Round 5
// 69.557 us; speedup vs baseline: 1.9697x; 1.0348x over previous
//
#include <hip/hip_runtime.h>

#define NB       128
#define M_TOTAL  8192
#define RESULT_FLOATS (M_TOTAL * 7)

typedef unsigned long long u64;
typedef unsigned int u32;

// One fused kernel. Grid = 256 blocks x 512 threads.
//   block b: tile tb = b>>2 (4 blocks per tile), sub = b&3.
//   Each block redundantly runs its tile's NMS and writes output for its
//   32 boxes (sub*32..+31).
// Global order key (tie-free, stable): aug = (sbits << 13) | (8191 - j),
// sbits = valid ? bits(score) : 0. rank_i = #{j : aug_j > aug_i}.
// Rank counting is register-blocked (keys in VGPRs vs 32 box-keys in VGPRs).
// Work split: waves 0-6 count keys [0,8064) (18/thread); wave 7 runs the
// serial greedy NMS scan on lane 0 and then counts the 128 leftover keys —
// the scan hides under the counting on waves 0-6.
__global__ __launch_bounds__(512) void fused_nms_kernel(
    const float* __restrict__ tr,    // [8192][7]
    const int*   __restrict__ tp,    // [64][4]
    float*       __restrict__ out)   // [8192*7] rows + [8192] keep
{
    __shared__ u64   s_boxaug[32];
    __shared__ u64   s_laug[NB];
    __shared__ float t_x1[NB], t_y1[NB], t_x2[NB], t_y2[NB], t_area[NB];
    __shared__ alignas(16) u32 sup32[NB][4];
    __shared__ u64   validmask[2];
    __shared__ u64   keepmask[2];
    __shared__ alignas(16) u32 s_wpart[8][16];   // packed u16 pairs per wave
    __shared__ int   s_p[NB];

    const int tid = threadIdx.x;
    const int wv  = tid >> 6;
    const int sub = blockIdx.x & 3;
    const int tb  = blockIdx.x >> 2;
    const int g0  = tb * NB;

    if (tid < 2) validmask[tid] = 0ull;

    // ---- score prefetch (issued first, long-latency) ----
    float sc[18];
    float sc2[2];
    int   j2 = 0;
    if (wv < 7) {
#pragma unroll
        for (int k = 0; k < 18; ++k)
            sc[k] = tr[(size_t)(tid + 448 * k) * 7 + 4];
    } else {
        j2 = 8064 + ((tid - 448) << 1);
        sc2[0] = tr[(size_t)j2 * 7 + 4];
        sc2[1] = tr[(size_t)(j2 + 1) * 7 + 4];
    }

    // ---- box keys for this block's 32 output boxes ----
    if (tid < 32) {
        int i = g0 + sub * 32 + tid;
        float s = tr[(size_t)i * 7 + 4];
        u32 sb = (s > 0.05f) ? __float_as_uint(s) : 0u;
        s_boxaug[tid] = ((u64)sb << 13) | (u64)(M_TOTAL - 1 - i);
    }

    // ---- per-box NMS compute (threads 0..127) ----
    float sx1 = 0.f, sy1 = 0.f, sx2 = 0.f, sy2 = 0.f, area = 0.f;
    u64 aug_n = 0;
    bool valid = false;
    if (tid < NB) {
        const float* row = tr + (size_t)(g0 + tid) * 7;
        float x1 = row[0], y1 = row[1], x2 = row[2], y2 = row[3];
        float score = row[4], label = row[5];
        float hf = (float)tp[tb * 4 + 0];
        float wf = (float)tp[tb * 4 + 2];
        float gx1 = fminf(fmaxf(__fadd_rn(x1, wf), 0.0f), 4096.0f);
        float gy1 = fminf(fmaxf(__fadd_rn(y1, hf), 0.0f), 4096.0f);
        float gx2 = fminf(fmaxf(__fadd_rn(x2, wf), 0.0f), 4096.0f);
        float gy2 = fminf(fmaxf(__fadd_rn(y2, hf), 0.0f), 4096.0f);
        valid = score > 0.05f;
        u32 sb = valid ? __float_as_uint(score) : 0u;
        aug_n = ((u64)sb << 13) | (u64)(M_TOTAL - 1 - (g0 + tid));
        float c = __fmul_rn(label, 8192.0f);
        sx1 = __fadd_rn(gx1, c);
        sy1 = __fadd_rn(gy1, c);
        sx2 = __fadd_rn(gx2, c);
        sy2 = __fadd_rn(gy2, c);
        area = __fmul_rn(__fsub_rn(sx2, sx1), __fsub_rn(sy2, sy1));
        s_laug[tid] = aug_n;
    }
    __syncthreads();                                    // b1

    // ---- 32 box keys into registers (LDS broadcast) ----
    u64 bk[32];
#pragma unroll
    for (int b = 0; b < 32; ++b) bk[b] = s_boxaug[b];

    // ---- local stable rank + scatter (threads 0..127) ----
    if (tid < NB) {
        int p = 0;
        const ulonglong2* lv = (const ulonglong2*)s_laug;
#pragma unroll 8
        for (int u = 0; u < 64; ++u) {
            ulonglong2 v = lv[u];
            p += (v.x > aug_n) + (v.y > aug_n);
        }
        t_x1[p] = sx1; t_y1[p] = sy1; t_x2[p] = sx2; t_y2[p] = sy2;
        t_area[p] = area;
        s_p[tid] = p;
        if (valid) atomicOr(&validmask[p >> 6], 1ull << (p & 63));
    }
    __syncthreads();                                    // b2

    // ---- suppression bitmatrix: thread -> (row r, col quarter cq) ----
    {
        int r = tid >> 2, cq = tid & 3;
        float rx1 = t_x1[r], ry1 = t_y1[r], rx2 = t_x2[r], ry2 = t_y2[r];
        float ra = t_area[r];
        u32 m = 0;
        int wbase = cq * 32;
#pragma unroll 4
        for (int w2 = 0; w2 < 32; ++w2) {
            int w = wbase + w2;
            float ltx = fmaxf(rx1, t_x1[w]);
            float lty = fmaxf(ry1, t_y1[w]);
            float rbx = fminf(rx2, t_x2[w]);
            float rby = fminf(ry2, t_y2[w]);
            float iw = fmaxf(__fsub_rn(rbx, ltx), 0.0f);
            float ih = fmaxf(__fsub_rn(rby, lty), 0.0f);
            float inter = __fmul_rn(iw, ih);
            float uni   = __fsub_rn(__fadd_rn(ra, t_area[w]), inter);
            float denom = __fadd_rn(uni, 1e-8f);
            float iou   = __fdiv_rn(inter, denom);
            bool s = (w > r) && (iou > 0.5f);
            m |= ((u32)s) << w2;
        }
        sup32[r][cq] = m;
    }
    __syncthreads();                                    // b3

    // ---- concurrent phase: waves 0-6 count; wave 7 scans then counts ----
    int cnt[32];
#pragma unroll
    for (int b = 0; b < 32; ++b) cnt[b] = 0;

    if (wv < 7) {
#pragma unroll
        for (int k = 0; k < 18; ++k) {
            int j = tid + 448 * k;
            u32 sb = (sc[k] > 0.05f) ? __float_as_uint(sc[k]) : 0u;
            u64 a = ((u64)sb << 13) | (u64)(M_TOTAL - 1 - j);
#pragma unroll
            for (int b = 0; b < 32; ++b) cnt[b] += (a > bk[b]);
        }
    } else {
        // serial greedy scan on lane 0 of wave 7 (hidden under counting)
        if (tid == 448) {
            const ulonglong2* supv = (const ulonglong2*)sup32;
            u64 v0 = validmask[0], v1 = validmask[1];
            u64 r0 = 0ull, r1 = 0ull;
            for (int c = 0; c < NB; c += 8) {
                ulonglong2 buf[8];
#pragma unroll
                for (int x = 0; x < 8; ++x) buf[x] = supv[c + x];
#pragma unroll
                for (int x = 0; x < 8; ++x) {
                    int q = c + x;
                    u64 alive = ((q < 64) ? ((v0 & ~r0) >> q)
                                          : ((v1 & ~r1) >> (q - 64))) & 1ull;
                    u64 take = 0ull - alive;
                    r0 |= buf[x].x & take;
                    r1 |= buf[x].y & take;
                }
            }
            keepmask[0] = v0 & ~r0;
            keepmask[1] = v1 & ~r1;
        }
        // leftover keys [8064, 8192): 2 per thread
#pragma unroll
        for (int k = 0; k < 2; ++k) {
            int j = j2 + k;
            float s = sc2[k];
            u32 sb = (s > 0.05f) ? __float_as_uint(s) : 0u;
            u64 a = ((u64)sb << 13) | (u64)(M_TOTAL - 1 - j);
#pragma unroll
            for (int b = 0; b < 32; ++b) cnt[b] += (a > bk[b]);
        }
    }

    // pack counter pairs (b, b+16) into u16 halves; totals <= 8191, no overflow
    u32 pk[16];
#pragma unroll
    for (int q = 0; q < 16; ++q)
        pk[q] = (u32)cnt[q] | ((u32)cnt[q + 16] << 16);

    // wave butterfly reduction (64 lanes)
#pragma unroll
    for (int q = 0; q < 16; ++q) {
        int c = (int)pk[q];
#pragma unroll
        for (int m = 1; m < 64; m <<= 1) c += __shfl_xor(c, m, 64);
        pk[q] = (u32)c;
    }
    {
        const int lane = tid & 63;
        if (lane == 0) {
            uint4* wp = (uint4*)&s_wpart[wv][0];
#pragma unroll
            for (int q4 = 0; q4 < 4; ++q4)
                wp[q4] = make_uint4(pk[4*q4], pk[4*q4+1], pk[4*q4+2], pk[4*q4+3]);
        }
    }
    __syncthreads();                                    // b4

    // ---- write this block's 32 boxes ----
    if (tid < 32) {
        int rank = 0;
        const int q = tid & 15;
        const int sh = (tid >> 4) << 4;
#pragma unroll
        for (int w = 0; w < 8; ++w)
            rank += (int)((s_wpart[w][q] >> sh) & 0xffffu);

        int nl = sub * 32 + tid;         // local box in tile
        int i  = g0 + nl;                // global box
        int pp = s_p[nl];
        float kf = ((keepmask[pp >> 6] >> (pp & 63)) & 1ull) ? 1.0f : 0.0f;

        const float* row = tr + (size_t)i * 7;
        float x1 = row[0], y1 = row[1], x2 = row[2], y2 = row[3];
        float score = row[4], label = row[5], growth = row[6];
        float hf = (float)tp[tb * 4 + 0];
        float wf = (float)tp[tb * 4 + 2];
        float gx1 = fminf(fmaxf(__fadd_rn(x1, wf), 0.0f), 4096.0f);
        float gy1 = fminf(fmaxf(__fadd_rn(y1, hf), 0.0f), 4096.0f);
        float gx2 = fminf(fmaxf(__fadd_rn(x2, wf), 0.0f), 4096.0f);
        float gy2 = fminf(fmaxf(__fadd_rn(y2, hf), 0.0f), 4096.0f);

        float* o = out + (size_t)rank * 7;
        o[0] = __fmul_rn(gx1, kf);
        o[1] = __fmul_rn(gy1, kf);
        o[2] = __fmul_rn(gx2, kf);
        o[3] = __fmul_rn(gy2, kf);
        o[4] = __fmul_rn(score, kf);
        o[5] = __fmul_rn(label, kf);
        o[6] = __fmul_rn(growth, kf);
        out[RESULT_FLOATS + rank] = kf;
    }
}

extern "C" void kernel_launch(void* const* d_in, const int* in_sizes, int n_in,
                              void* d_out, int out_size, void* d_ws, size_t ws_size,
                              hipStream_t stream) {
    const float* tile_results   = (const float*)d_in[0];
    const int*   tile_positions = (const int*)d_in[1];
    float* out = (float*)d_out;

    hipLaunchKernelGGL(fused_nms_kernel, dim3(256), dim3(512), 0, stream,
                       tile_results, tile_positions, out);
}